// Round 8
// baseline (196.212 us; speedup 1.0000x reference)
//
#include <hip/hip_runtime.h>
#include <hip/hip_bf16.h>

#define NN 100000
#define NE 800000
#define NG 2000
#define EMB 64
#define HID 128
#define NCLS 10

#define NBKT 196                       // coarse dst buckets (512 nodes each)
#define EPB 4096                       // edges per counting block
#define NBA ((NE + EPB - 1) / EPB)     // 196 counting blocks
#define NSCAN (NBKT * NBA)             // 38416
#define GS_NB ((NSCAN + 511) / 512)    // 76

typedef __attribute__((ext_vector_type(8))) short short8;
typedef __attribute__((ext_vector_type(4))) float f32x4;
typedef unsigned short u16;
typedef unsigned int u32;

// monotone float<->uint encoding so unsigned atomicMax == float max
static __device__ __forceinline__ unsigned fenc(float f) {
    unsigned u = __float_as_uint(f);
    return (u & 0x80000000u) ? ~u : (u | 0x80000000u);
}
static __device__ __forceinline__ float fdec(unsigned u) {
    return (u & 0x80000000u) ? __uint_as_float(u & 0x7FFFFFFFu) : __uint_as_float(~u);
}
static __device__ __forceinline__ u16 f2bf(float f) {
    u32 u = __float_as_uint(f);
    return (u16)((u + 0x7FFFu + ((u >> 16) & 1u)) >> 16);
}

__global__ void k_init(unsigned* genc, float* relp, u16* Bt1, u16* Bt2,
                       const float* rel_table, const float* w1l, const float* w1r,
                       const float* w2l, const float* w2r) {
    int i = blockIdx.x * 256 + threadIdx.x;   // grid covers 256000
    if (i < NG * HID) genc[i] = 0x007FFFFFu;  // fenc(-inf)
    if (i < 3 * HID) {
        int t = i >> 7, j = i & 127;
        float s = 0.f;
        for (int k = 0; k < 16; ++k)
            s += rel_table[t * 16 + k] * w1l[(64 + k) * HID + j];
        relp[i] = s;
    }
    if (i < 128 * 128) {   // Bt1[c][k] = B1[k][c], B1 = [w1l[0:64]; w1r]
        int c = i >> 7, k = i & 127;
        float w = (k < 64) ? w1l[k * HID + c] : w1r[(k - 64) * HID + c];
        Bt1[c * 128 + k] = f2bf(w);
    }
    if (i < 128 * 256) {   // Bt2[c][k] = B2[k][c], B2 = [w2l; w2r]
        int c = i >> 8, k = i & 255;
        float w = (k < 128) ? w2l[k * HID + c] : w2r[(k - 128) * HID + c];
        Bt2[c * 256 + k] = f2bf(w);
    }
}

// embedding gather -> bf16 into x-half of ax[node][128] (cols 64..127)
__global__ void k_embed(const int* __restrict__ tok, const float* __restrict__ emb,
                        u32* __restrict__ axw) {
    int i = blockIdx.x * 256 + threadIdx.x;   // < NN*32
    int n = i >> 5, p = i & 31;
    float2 e = *(const float2*)&emb[tok[n] * EMB + p * 2];
    axw[n * 64 + 32 + p] = (u32)f2bf(e.x) | ((u32)f2bf(e.y) << 16);
}

// ---- atomic-free CSR build: two-level counting sort by dst ----

__global__ __launch_bounds__(256) void k_cnt(const int* __restrict__ dst,
                                             int* __restrict__ counts) {
    __shared__ int hist[NBKT];
    int t = threadIdx.x;
    for (int i = t; i < NBKT; i += 256) hist[i] = 0;
    __syncthreads();
    int base = blockIdx.x * EPB;
    for (int j = t; j < EPB; j += 256) {
        int e = base + j;
        if (e < NE) atomicAdd(&hist[dst[e] >> 9], 1);
    }
    __syncthreads();
    for (int i = t; i < NBKT; i += 256)
        counts[i * NBA + blockIdx.x] = hist[i];  // bucket-major for scan
}

__global__ __launch_bounds__(256) void k_gs1(const int* __restrict__ v, int* __restrict__ part) {
    __shared__ int ws[4];
    int t = threadIdx.x;
    int i0 = blockIdx.x * 512 + t * 2;
    int e0 = (i0 < NSCAN) ? v[i0] : 0;
    int e1 = (i0 + 1 < NSCAN) ? v[i0 + 1] : 0;
    int s = e0 + e1;
    for (int off = 32; off > 0; off >>= 1) s += __shfl_down(s, off, 64);
    if ((t & 63) == 0) ws[t >> 6] = s;
    __syncthreads();
    if (t == 0) part[blockIdx.x] = ws[0] + ws[1] + ws[2] + ws[3];
}

__global__ __launch_bounds__(128) void k_gs2(int* __restrict__ part) {
    __shared__ int s[128];
    int t = threadIdx.x;
    int v = (t < GS_NB) ? part[t] : 0;
    s[t] = v;
    __syncthreads();
    for (int off = 1; off < 128; off <<= 1) {
        int u = (t >= off) ? s[t - off] : 0;
        __syncthreads();
        s[t] += u;
        __syncthreads();
    }
    if (t < GS_NB) part[t] = s[t] - v;  // exclusive
}

__global__ __launch_bounds__(256) void k_gs3(const int* __restrict__ v,
                                             const int* __restrict__ part,
                                             int* __restrict__ out) {
    __shared__ int s[256];
    int t = threadIdx.x;
    int i0 = blockIdx.x * 512 + t * 2;
    int e0 = (i0 < NSCAN) ? v[i0] : 0;
    int e1 = (i0 + 1 < NSCAN) ? v[i0 + 1] : 0;
    int tsum = e0 + e1;
    s[t] = tsum;
    __syncthreads();
    for (int off = 1; off < 256; off <<= 1) {
        int u = (t >= off) ? s[t - off] : 0;
        __syncthreads();
        s[t] += u;
        __syncthreads();
    }
    int p0 = part[blockIdx.x] + s[t] - tsum;
    if (i0 < NSCAN) out[i0] = p0;
    if (i0 + 1 < NSCAN) out[i0 + 1] = p0 + e0;
}

// pack: src(17) | etype(2)<<17 | dstlow(9)<<19
__global__ __launch_bounds__(256) void k_part(const int* __restrict__ src,
                                              const int* __restrict__ dst,
                                              const int* __restrict__ et,
                                              const int* __restrict__ scanned,
                                              u32* __restrict__ coarse) {
    __shared__ int cur[NBKT];
    int t = threadIdx.x;
    for (int i = t; i < NBKT; i += 256) cur[i] = scanned[i * NBA + blockIdx.x];
    __syncthreads();
    int base = blockIdx.x * EPB;
    for (int j = t; j < EPB; j += 256) {
        int e = base + j;
        if (e < NE) {
            int d = dst[e];
            int pos = atomicAdd(&cur[d >> 9], 1);
            coarse[pos] = (u32)src[e] | ((u32)et[e] << 17) | ((u32)(d & 511) << 19);
        }
    }
}

__global__ __launch_bounds__(256) void k_csr(const int* __restrict__ scanned,
                                             const u32* __restrict__ coarse,
                                             int* __restrict__ offsets,
                                             int* __restrict__ packed) {
    __shared__ int hist[512];
    __shared__ int ex[512];
    __shared__ int ts[256];
    int b = blockIdx.x, t = threadIdx.x;
    int beg = scanned[b * NBA];
    int end = (b + 1 < NBKT) ? scanned[(b + 1) * NBA] : NE;
    hist[t] = 0; hist[t + 256] = 0;
    __syncthreads();
    for (int i = beg + t; i < end; i += 256)
        atomicAdd(&hist[(coarse[i] >> 19) & 511], 1);
    __syncthreads();
    int a0 = hist[2 * t], a1 = hist[2 * t + 1];
    int sum = a0 + a1;
    ts[t] = sum;
    __syncthreads();
    for (int off = 1; off < 256; off <<= 1) {
        int u = (t >= off) ? ts[t - off] : 0;
        __syncthreads();
        ts[t] += u;
        __syncthreads();
    }
    int ep = ts[t] - sum;
    ex[2 * t] = ep;
    ex[2 * t + 1] = ep + a0;
    __syncthreads();
    int node0 = b * 512;
    if (node0 + 2 * t < NN)     offsets[node0 + 2 * t]     = beg + ex[2 * t];
    if (node0 + 2 * t + 1 < NN) offsets[node0 + 2 * t + 1] = beg + ex[2 * t + 1];
    if (b == NBKT - 1 && t == 0) offsets[NN] = NE;
    hist[2 * t] = beg + ex[2 * t];
    hist[2 * t + 1] = beg + ex[2 * t + 1];
    __syncthreads();
    for (int i = beg + t; i < end; i += 256) {
        u32 pk = coarse[i];
        int pos = atomicAdd(&hist[(pk >> 19) & 511], 1);
        packed[pos] = (int)(pk & 0x1FFFFu) | (int)(((pk >> 17) & 3u) << 20);
    }
}

// gather: mean of x[src] + relation-type fractions into agg-half of ax.
__global__ __launch_bounds__(256) void k_agg1(
    const int* __restrict__ offsets, const int* __restrict__ packed,
    u32* __restrict__ axw, float* __restrict__ fc) {
    int node = (blockIdx.x * 256 + threadIdx.x) >> 6;
    int lane = threadIdx.x & 63;
    int half = lane >> 5;
    int fl = lane & 31;
    int beg = offsets[node], end = offsets[node + 1];
    float a0 = 0.f, a1 = 0.f;
    int c0 = 0, c1 = 0, c2 = 0;
    for (int cb = beg; cb < end; cb += 64) {
        int pk = packed[min(cb + lane, NE - 1)];
        int cnt = min(end - cb, 64);
        int j = 0;
        for (; j + 8 <= cnt; j += 8) {
            #pragma unroll
            for (int q = 0; q < 4; ++q) {
                int p = __shfl(pk, j + q * 2 + half, 64);
                u32 v = axw[(p & 0xFFFFF) * 64 + 32 + fl];
                a0 += __uint_as_float(v << 16);
                a1 += __uint_as_float(v & 0xFFFF0000u);
                int t = p >> 20;
                c0 += (t == 0); c1 += (t == 1); c2 += (t == 2);
            }
        }
        for (; j < cnt; j += 2) {
            int idx = j + half;
            if (idx < cnt) {
                int p = __shfl(pk, idx, 64);
                u32 v = axw[(p & 0xFFFFF) * 64 + 32 + fl];
                a0 += __uint_as_float(v << 16);
                a1 += __uint_as_float(v & 0xFFFF0000u);
                int t = p >> 20;
                c0 += (t == 0); c1 += (t == 1); c2 += (t == 2);
            }
        }
    }
    a0 += __shfl_xor(a0, 32, 64);
    a1 += __shfl_xor(a1, 32, 64);
    c0 += __shfl_xor(c0, 32, 64);
    c1 += __shfl_xor(c1, 32, 64);
    c2 += __shfl_xor(c2, 32, 64);
    float inv = 1.0f / (float)max(end - beg, 1);
    if (half == 0)
        axw[node * 64 + fl] = (u32)f2bf(a0 * inv) | ((u32)f2bf(a1 * inv) << 16);
    if (lane == 0)
        *(float4*)&fc[node * 4] = make_float4(c0 * inv, c1 * inv, c2 * inv, 0.f);
}

// gather: mean of h[src] (h-half of ah) into agg-half of ah. One wave per node.
__global__ __launch_bounds__(256) void k_agg2(
    const int* __restrict__ offsets, const int* __restrict__ packed,
    u32* __restrict__ ahw) {
    int node = (blockIdx.x * 256 + threadIdx.x) >> 6;
    int lane = threadIdx.x & 63;
    int beg = offsets[node], end = offsets[node + 1];
    float a0 = 0.f, a1 = 0.f;
    for (int cb = beg; cb < end; cb += 64) {
        int pk = packed[min(cb + lane, NE - 1)] & 0xFFFFF;
        int cnt = min(end - cb, 64);
        int j = 0;
        for (; j + 4 <= cnt; j += 4) {
            int s0 = __shfl(pk, j, 64), s1 = __shfl(pk, j + 1, 64);
            int s2 = __shfl(pk, j + 2, 64), s3 = __shfl(pk, j + 3, 64);
            u32 u0 = ahw[(size_t)s0 * 128 + 64 + lane];
            u32 u1 = ahw[(size_t)s1 * 128 + 64 + lane];
            u32 u2 = ahw[(size_t)s2 * 128 + 64 + lane];
            u32 u3 = ahw[(size_t)s3 * 128 + 64 + lane];
            a0 += __uint_as_float(u0 << 16) + __uint_as_float(u1 << 16)
                + __uint_as_float(u2 << 16) + __uint_as_float(u3 << 16);
            a1 += __uint_as_float(u0 & 0xFFFF0000u) + __uint_as_float(u1 & 0xFFFF0000u)
                + __uint_as_float(u2 & 0xFFFF0000u) + __uint_as_float(u3 & 0xFFFF0000u);
        }
        for (; j < cnt; ++j) {
            u32 u = ahw[(size_t)__shfl(pk, j, 64) * 128 + 64 + lane];
            a0 += __uint_as_float(u << 16);
            a1 += __uint_as_float(u & 0xFFFF0000u);
        }
    }
    float inv = 1.0f / (float)max(end - beg, 1);
    ahw[node * 128 + lane] = (u32)f2bf(a0 * inv) | ((u32)f2bf(a1 * inv) << 16);
}

// MFMA GEMM layer1: M=128/block, 8 waves, wave tile 16x128, K=128.
// A = ax rows (contiguous [aggx|x]); all 4 A-frags preloaded to regs; B swizzled in LDS.
__global__ __launch_bounds__(512) void k_gemm1(
    const u16* __restrict__ ax, const float* __restrict__ fc,
    const u16* __restrict__ Bt1, const float* __restrict__ b1,
    const float* __restrict__ relp, u16* __restrict__ ah) {
    __shared__ u16 Bs[128 * 128];   // 32KB; row = 16 chunks; slot p holds chunk p^(col&7)
    int tid = threadIdx.x;
    int lane = tid & 63, w = tid >> 6;
    int mbase = blockIdx.x * 128;
    int r16 = lane & 15;
    int kg = (lane >> 4) * 8;
    int r = min(mbase + w * 16 + r16, NN - 1);
    short8 a[4];
    #pragma unroll
    for (int s = 0; s < 4; ++s)
        a[s] = *(const short8*)(ax + (size_t)r * 128 + s * 32 + kg);
    for (int i = tid; i < 2048; i += 512) {
        int col = i >> 4, p = i & 15;
        ((short8*)Bs)[i] = *(const short8*)(Bt1 + col * 128 + ((p ^ (col & 7)) << 3));
    }
    __syncthreads();
    f32x4 acc[8] = {};
    #pragma unroll
    for (int s = 0; s < 4; ++s) {
        int c = s * 4 + (lane >> 4);
        #pragma unroll
        for (int nf = 0; nf < 8; ++nf) {
            int col = nf * 16 + r16;
            short8 b = ((const short8*)Bs)[col * 16 + (c ^ (col & 7))];
            acc[nf] = __builtin_amdgcn_mfma_f32_16x16x32_bf16(a[s], b, acc[nf], 0, 0, 0);
        }
    }
    #pragma unroll
    for (int reg = 0; reg < 4; ++reg) {
        int row = mbase + w * 16 + (lane >> 4) * 4 + reg;
        if (row >= NN) continue;
        float4 f = *(const float4*)&fc[row * 4];
        #pragma unroll
        for (int nf = 0; nf < 8; ++nf) {
            int cc = nf * 16 + r16;
            float v = acc[nf][reg] + b1[cc]
                    + f.x * relp[cc] + f.y * relp[128 + cc] + f.z * relp[256 + cc];
            ah[(size_t)row * 256 + 128 + cc] = f2bf(fmaxf(v, 0.f));
        }
    }
}

// MFMA GEMM layer2: M=128/block, 8 waves, wave tile 16x128, K=256.
// A = ah rows (contiguous [aggh|h]); all 8 A-frags preloaded; B swizzled in LDS; pooled max.
__global__ __launch_bounds__(512) void k_gemm2(
    const u16* __restrict__ ah, const u16* __restrict__ Bt2,
    const float* __restrict__ b2, const int* __restrict__ batch,
    unsigned* __restrict__ genc) {
    __shared__ u16 Bs[128 * 256];   // 64KB; row = 32 chunks; slot p holds chunk p^(col&7)
    int tid = threadIdx.x;
    int lane = tid & 63, w = tid >> 6;
    int mbase = blockIdx.x * 128;
    int r16 = lane & 15;
    int kg = (lane >> 4) * 8;
    int r = min(mbase + w * 16 + r16, NN - 1);
    short8 a[8];
    #pragma unroll
    for (int s = 0; s < 8; ++s)
        a[s] = *(const short8*)(ah + (size_t)r * 256 + s * 32 + kg);
    for (int i = tid; i < 4096; i += 512) {
        int col = i >> 5, p = i & 31;
        ((short8*)Bs)[i] = *(const short8*)(Bt2 + col * 256 + ((p ^ (col & 7)) << 3));
    }
    __syncthreads();
    f32x4 acc[8] = {};
    #pragma unroll
    for (int s = 0; s < 8; ++s) {
        int c = s * 4 + (lane >> 4);
        #pragma unroll
        for (int nf = 0; nf < 8; ++nf) {
            int col = nf * 16 + r16;
            short8 b = ((const short8*)Bs)[col * 32 + (c ^ (col & 7))];
            acc[nf] = __builtin_amdgcn_mfma_f32_16x16x32_bf16(a[s], b, acc[nf], 0, 0, 0);
        }
    }
    float bv[8];
    #pragma unroll
    for (int nf = 0; nf < 8; ++nf) bv[nf] = b2[nf * 16 + r16];
    int r0 = mbase + w * 16 + (lane >> 4) * 4;
    if (r0 < NN) {
        if (r0 + 3 < NN && batch[r0] == batch[r0 + 3]) {
            int bt = batch[r0];
            #pragma unroll
            for (int nf = 0; nf < 8; ++nf) {
                int cc = nf * 16 + r16;
                f32x4 v4 = acc[nf];
                float v = fmaxf(fmaxf(v4[0], v4[1]), fmaxf(v4[2], v4[3])) + bv[nf];
                atomicMax(&genc[bt * HID + cc], fenc(v));
            }
        } else {
            #pragma unroll
            for (int reg = 0; reg < 4; ++reg) {
                int row = r0 + reg;
                if (row >= NN) continue;
                int bt = batch[row];
                #pragma unroll
                for (int nf = 0; nf < 8; ++nf) {
                    int cc = nf * 16 + r16;
                    atomicMax(&genc[bt * HID + cc], fenc(acc[nf][reg] + bv[nf]));
                }
            }
        }
    }
}

__global__ void k_final(const unsigned* __restrict__ genc,
                        const float* __restrict__ lin_w, const float* __restrict__ lin_b,
                        float* __restrict__ out) {
    int gr = blockIdx.x;
    int lane = threadIdx.x;  // 64
    float g0 = fmaxf(fdec(genc[gr * HID + lane]), 0.f);
    float g1 = fmaxf(fdec(genc[gr * HID + 64 + lane]), 0.f);
    #pragma unroll
    for (int c = 0; c < NCLS; ++c) {
        float p = g0 * lin_w[lane * NCLS + c] + g1 * lin_w[(lane + 64) * NCLS + c];
        for (int off = 32; off > 0; off >>= 1)
            p += __shfl_down(p, off, 64);
        if (lane == 0) out[gr * NCLS + c] = p + lin_b[c];
    }
}

extern "C" void kernel_launch(void* const* d_in, const int* in_sizes, int n_in,
                              void* d_out, int out_size, void* d_ws, size_t ws_size,
                              hipStream_t stream) {
    const int* x_tokens   = (const int*)d_in[0];
    const int* edge_index = (const int*)d_in[1];
    const int* edge_type  = (const int*)d_in[2];
    const int* batch      = (const int*)d_in[3];
    const float* emb_table = (const float*)d_in[5];
    const float* rel_table = (const float*)d_in[6];
    const float* w1_l = (const float*)d_in[7];
    const float* b1   = (const float*)d_in[8];
    const float* w1_r = (const float*)d_in[9];
    const float* w2_l = (const float*)d_in[10];
    const float* b2   = (const float*)d_in[11];
    const float* w2_r = (const float*)d_in[12];
    const float* lin_w = (const float*)d_in[13];
    const float* lin_b = (const float*)d_in[14];
    float* out = (float*)d_out;

    const int* src = edge_index;
    const int* dst = edge_index + NE;

    char* ws = (char*)d_ws;
    size_t off = 0;
    auto alloc = [&](size_t bytes) {
        void* p = ws + off;
        off = (off + bytes + 255) & ~(size_t)255;
        return p;
    };
    u16* ax      = (u16*)alloc((size_t)NN * 128 * 2);    // 25.6 MB  [aggx | x]
    u16* ah      = (u16*)alloc((size_t)NN * 256 * 2);    // 51.2 MB  [aggh | h]
    float* fc    = (float*)alloc((size_t)NN * 4 * 4);
    int* offsets = (int*)alloc((size_t)(NN + 1) * 4);
    int* packed  = (int*)alloc((size_t)NE * 4);
    u32* coarse  = (u32*)alloc((size_t)NE * 4);
    int* counts  = (int*)alloc((size_t)NSCAN * 4);
    int* scanned = (int*)alloc((size_t)NSCAN * 4);
    int* gpart   = (int*)alloc((size_t)128 * 4);
    unsigned* genc = (unsigned*)alloc((size_t)NG * HID * 4);
    float* relp  = (float*)alloc((size_t)3 * HID * 4);
    u16* Bt1     = (u16*)alloc((size_t)128 * 128 * 2);
    u16* Bt2     = (u16*)alloc((size_t)128 * 256 * 2);
    (void)ws_size; (void)in_sizes; (void)n_in; (void)out_size;

    const int MT = (NN + 127) / 128;  // 782 GEMM m-tiles

    hipLaunchKernelGGL(k_init,  dim3(1000), dim3(256), 0, stream,
                       genc, relp, Bt1, Bt2, rel_table, w1_l, w1_r, w2_l, w2_r);
    hipLaunchKernelGGL(k_embed, dim3(NN * 32 / 256), dim3(256), 0, stream,
                       x_tokens, emb_table, (u32*)ax);
    hipLaunchKernelGGL(k_cnt,   dim3(NBA), dim3(256), 0, stream, dst, counts);
    hipLaunchKernelGGL(k_gs1,   dim3(GS_NB), dim3(256), 0, stream, counts, gpart);
    hipLaunchKernelGGL(k_gs2,   dim3(1), dim3(128), 0, stream, gpart);
    hipLaunchKernelGGL(k_gs3,   dim3(GS_NB), dim3(256), 0, stream, counts, gpart, scanned);
    hipLaunchKernelGGL(k_part,  dim3(NBA), dim3(256), 0, stream,
                       src, dst, edge_type, scanned, coarse);
    hipLaunchKernelGGL(k_csr,   dim3(NBKT), dim3(256), 0, stream,
                       scanned, coarse, offsets, packed);
    hipLaunchKernelGGL(k_agg1,  dim3(NN / 4), dim3(256), 0, stream,
                       offsets, packed, (u32*)ax, fc);
    hipLaunchKernelGGL(k_gemm1, dim3(MT), dim3(512), 0, stream,
                       ax, fc, Bt1, b1, relp, ah);
    hipLaunchKernelGGL(k_agg2,  dim3(NN / 4), dim3(256), 0, stream,
                       offsets, packed, (u32*)ah);
    hipLaunchKernelGGL(k_gemm2, dim3(MT), dim3(512), 0, stream,
                       ah, Bt2, b2, batch, genc);
    hipLaunchKernelGGL(k_final, dim3(NG), dim3(64), 0, stream, genc, lin_w, lin_b, out);
}

// Round 9
// 177.599 us; speedup vs baseline: 1.1048x; 1.1048x over previous
//
#include <hip/hip_runtime.h>
#include <hip/hip_bf16.h>

#define NN 100000
#define NE 800000
#define NG 2000
#define EMB 64
#define HID 128
#define NCLS 10

#define NBKT 196                       // coarse dst buckets (512 nodes each)
#define EPB 4096                       // edges per counting block
#define NBA ((NE + EPB - 1) / EPB)     // 196 counting blocks
#define NSCAN (NBKT * NBA)             // 38416
#define GS_NB ((NSCAN + 511) / 512)    // 76

typedef __attribute__((ext_vector_type(8))) short short8;
typedef __attribute__((ext_vector_type(4))) float f32x4;
typedef unsigned short u16;
typedef unsigned int u32;

// monotone float<->uint encoding so unsigned atomicMax == float max
static __device__ __forceinline__ unsigned fenc(float f) {
    unsigned u = __float_as_uint(f);
    return (u & 0x80000000u) ? ~u : (u | 0x80000000u);
}
static __device__ __forceinline__ float fdec(unsigned u) {
    return (u & 0x80000000u) ? __uint_as_float(u & 0x7FFFFFFFu) : __uint_as_float(~u);
}
static __device__ __forceinline__ u16 f2bf(float f) {
    u32 u = __float_as_uint(f);
    return (u16)((u + 0x7FFFu + ((u >> 16) & 1u)) >> 16);
}

__global__ void k_init(unsigned* genc, float* relp, u16* Bt1, u16* Bt2,
                       const float* rel_table, const float* w1l, const float* w1r,
                       const float* w2l, const float* w2r) {
    int i = blockIdx.x * 256 + threadIdx.x;   // grid covers 256000
    if (i < NG * HID) genc[i] = 0x007FFFFFu;  // fenc(-inf)
    if (i < 3 * HID) {
        int t = i >> 7, j = i & 127;
        float s = 0.f;
        for (int k = 0; k < 16; ++k)
            s += rel_table[t * 16 + k] * w1l[(64 + k) * HID + j];
        relp[i] = s;
    }
    if (i < 128 * 128) {   // Bt1[c][k] = B1[k][c], B1 = [w1l[0:64]; w1r]
        int c = i >> 7, k = i & 127;
        float w = (k < 64) ? w1l[k * HID + c] : w1r[(k - 64) * HID + c];
        Bt1[c * 128 + k] = f2bf(w);
    }
    if (i < 128 * 256) {   // Bt2[c][k] = B2[k][c], B2 = [w2l; w2r]
        int c = i >> 8, k = i & 255;
        float w = (k < 128) ? w2l[k * HID + c] : w2r[(k - 128) * HID + c];
        Bt2[c * 256 + k] = f2bf(w);
    }
}

// embedding gather -> bf16 into x-half of ax[node][128] (cols 64..127)
__global__ void k_embed(const int* __restrict__ tok, const float* __restrict__ emb,
                        u32* __restrict__ axw) {
    int i = blockIdx.x * 256 + threadIdx.x;   // < NN*32
    int n = i >> 5, p = i & 31;
    float2 e = *(const float2*)&emb[tok[n] * EMB + p * 2];
    axw[n * 64 + 32 + p] = (u32)f2bf(e.x) | ((u32)f2bf(e.y) << 16);
}

// ---- atomic-free CSR build: two-level counting sort by dst ----

__global__ __launch_bounds__(256) void k_cnt(const int* __restrict__ dst,
                                             int* __restrict__ counts) {
    __shared__ int hist[NBKT];
    int t = threadIdx.x;
    for (int i = t; i < NBKT; i += 256) hist[i] = 0;
    __syncthreads();
    int base = blockIdx.x * EPB;
    for (int j = t; j < EPB; j += 256) {
        int e = base + j;
        if (e < NE) atomicAdd(&hist[dst[e] >> 9], 1);
    }
    __syncthreads();
    for (int i = t; i < NBKT; i += 256)
        counts[i * NBA + blockIdx.x] = hist[i];  // bucket-major for scan
}

__global__ __launch_bounds__(256) void k_gs1(const int* __restrict__ v, int* __restrict__ part) {
    __shared__ int ws[4];
    int t = threadIdx.x;
    int i0 = blockIdx.x * 512 + t * 2;
    int e0 = (i0 < NSCAN) ? v[i0] : 0;
    int e1 = (i0 + 1 < NSCAN) ? v[i0 + 1] : 0;
    int s = e0 + e1;
    for (int off = 32; off > 0; off >>= 1) s += __shfl_down(s, off, 64);
    if ((t & 63) == 0) ws[t >> 6] = s;
    __syncthreads();
    if (t == 0) part[blockIdx.x] = ws[0] + ws[1] + ws[2] + ws[3];
}

__global__ __launch_bounds__(128) void k_gs2(int* __restrict__ part) {
    __shared__ int s[128];
    int t = threadIdx.x;
    int v = (t < GS_NB) ? part[t] : 0;
    s[t] = v;
    __syncthreads();
    for (int off = 1; off < 128; off <<= 1) {
        int u = (t >= off) ? s[t - off] : 0;
        __syncthreads();
        s[t] += u;
        __syncthreads();
    }
    if (t < GS_NB) part[t] = s[t] - v;  // exclusive
}

__global__ __launch_bounds__(256) void k_gs3(const int* __restrict__ v,
                                             const int* __restrict__ part,
                                             int* __restrict__ out) {
    __shared__ int s[256];
    int t = threadIdx.x;
    int i0 = blockIdx.x * 512 + t * 2;
    int e0 = (i0 < NSCAN) ? v[i0] : 0;
    int e1 = (i0 + 1 < NSCAN) ? v[i0 + 1] : 0;
    int tsum = e0 + e1;
    s[t] = tsum;
    __syncthreads();
    for (int off = 1; off < 256; off <<= 1) {
        int u = (t >= off) ? s[t - off] : 0;
        __syncthreads();
        s[t] += u;
        __syncthreads();
    }
    int p0 = part[blockIdx.x] + s[t] - tsum;
    if (i0 < NSCAN) out[i0] = p0;
    if (i0 + 1 < NSCAN) out[i0 + 1] = p0 + e0;
}

// pack: src(17) | etype(2)<<17 | dstlow(9)<<19
__global__ __launch_bounds__(256) void k_part(const int* __restrict__ src,
                                              const int* __restrict__ dst,
                                              const int* __restrict__ et,
                                              const int* __restrict__ scanned,
                                              u32* __restrict__ coarse) {
    __shared__ int cur[NBKT];
    int t = threadIdx.x;
    for (int i = t; i < NBKT; i += 256) cur[i] = scanned[i * NBA + blockIdx.x];
    __syncthreads();
    int base = blockIdx.x * EPB;
    for (int j = t; j < EPB; j += 256) {
        int e = base + j;
        if (e < NE) {
            int d = dst[e];
            int pos = atomicAdd(&cur[d >> 9], 1);
            coarse[pos] = (u32)src[e] | ((u32)et[e] << 17) | ((u32)(d & 511) << 19);
        }
    }
}

__global__ __launch_bounds__(256) void k_csr(const int* __restrict__ scanned,
                                             const u32* __restrict__ coarse,
                                             int* __restrict__ offsets,
                                             int* __restrict__ packed) {
    __shared__ int hist[512];
    __shared__ int ex[512];
    __shared__ int ts[256];
    int b = blockIdx.x, t = threadIdx.x;
    int beg = scanned[b * NBA];
    int end = (b + 1 < NBKT) ? scanned[(b + 1) * NBA] : NE;
    hist[t] = 0; hist[t + 256] = 0;
    __syncthreads();
    for (int i = beg + t; i < end; i += 256)
        atomicAdd(&hist[(coarse[i] >> 19) & 511], 1);
    __syncthreads();
    int a0 = hist[2 * t], a1 = hist[2 * t + 1];
    int sum = a0 + a1;
    ts[t] = sum;
    __syncthreads();
    for (int off = 1; off < 256; off <<= 1) {
        int u = (t >= off) ? ts[t - off] : 0;
        __syncthreads();
        ts[t] += u;
        __syncthreads();
    }
    int ep = ts[t] - sum;
    ex[2 * t] = ep;
    ex[2 * t + 1] = ep + a0;
    __syncthreads();
    int node0 = b * 512;
    if (node0 + 2 * t < NN)     offsets[node0 + 2 * t]     = beg + ex[2 * t];
    if (node0 + 2 * t + 1 < NN) offsets[node0 + 2 * t + 1] = beg + ex[2 * t + 1];
    if (b == NBKT - 1 && t == 0) offsets[NN] = NE;
    hist[2 * t] = beg + ex[2 * t];
    hist[2 * t + 1] = beg + ex[2 * t + 1];
    __syncthreads();
    for (int i = beg + t; i < end; i += 256) {
        u32 pk = coarse[i];
        int pos = atomicAdd(&hist[(pk >> 19) & 511], 1);
        packed[pos] = (int)(pk & 0x1FFFFu) | (int)(((pk >> 17) & 3u) << 20);
    }
}

// gather: mean of x[src] + relation-type fractions into agg-half of ax.
__global__ __launch_bounds__(256) void k_agg1(
    const int* __restrict__ offsets, const int* __restrict__ packed,
    u32* __restrict__ axw, float* __restrict__ fc) {
    int node = (blockIdx.x * 256 + threadIdx.x) >> 6;
    int lane = threadIdx.x & 63;
    int half = lane >> 5;
    int fl = lane & 31;
    int beg = offsets[node], end = offsets[node + 1];
    float a0 = 0.f, a1 = 0.f;
    int c0 = 0, c1 = 0, c2 = 0;
    for (int cb = beg; cb < end; cb += 64) {
        int pk = packed[min(cb + lane, NE - 1)];
        int cnt = min(end - cb, 64);
        int j = 0;
        for (; j + 8 <= cnt; j += 8) {
            #pragma unroll
            for (int q = 0; q < 4; ++q) {
                int p = __shfl(pk, j + q * 2 + half, 64);
                u32 v = axw[(p & 0xFFFFF) * 64 + 32 + fl];
                a0 += __uint_as_float(v << 16);
                a1 += __uint_as_float(v & 0xFFFF0000u);
                int t = p >> 20;
                c0 += (t == 0); c1 += (t == 1); c2 += (t == 2);
            }
        }
        for (; j < cnt; j += 2) {
            int idx = j + half;
            if (idx < cnt) {
                int p = __shfl(pk, idx, 64);
                u32 v = axw[(p & 0xFFFFF) * 64 + 32 + fl];
                a0 += __uint_as_float(v << 16);
                a1 += __uint_as_float(v & 0xFFFF0000u);
                int t = p >> 20;
                c0 += (t == 0); c1 += (t == 1); c2 += (t == 2);
            }
        }
    }
    a0 += __shfl_xor(a0, 32, 64);
    a1 += __shfl_xor(a1, 32, 64);
    c0 += __shfl_xor(c0, 32, 64);
    c1 += __shfl_xor(c1, 32, 64);
    c2 += __shfl_xor(c2, 32, 64);
    float inv = 1.0f / (float)max(end - beg, 1);
    if (half == 0)
        axw[node * 64 + fl] = (u32)f2bf(a0 * inv) | ((u32)f2bf(a1 * inv) << 16);
    if (lane == 0)
        *(float4*)&fc[node * 4] = make_float4(c0 * inv, c1 * inv, c2 * inv, 0.f);
}

// gather: mean of h[src] (h-half of ah) into agg-half of ah. One wave per node.
__global__ __launch_bounds__(256) void k_agg2(
    const int* __restrict__ offsets, const int* __restrict__ packed,
    u32* __restrict__ ahw) {
    int node = (blockIdx.x * 256 + threadIdx.x) >> 6;
    int lane = threadIdx.x & 63;
    int beg = offsets[node], end = offsets[node + 1];
    float a0 = 0.f, a1 = 0.f;
    for (int cb = beg; cb < end; cb += 64) {
        int pk = packed[min(cb + lane, NE - 1)] & 0xFFFFF;
        int cnt = min(end - cb, 64);
        int j = 0;
        for (; j + 4 <= cnt; j += 4) {
            int s0 = __shfl(pk, j, 64), s1 = __shfl(pk, j + 1, 64);
            int s2 = __shfl(pk, j + 2, 64), s3 = __shfl(pk, j + 3, 64);
            u32 u0 = ahw[(size_t)s0 * 128 + 64 + lane];
            u32 u1 = ahw[(size_t)s1 * 128 + 64 + lane];
            u32 u2 = ahw[(size_t)s2 * 128 + 64 + lane];
            u32 u3 = ahw[(size_t)s3 * 128 + 64 + lane];
            a0 += __uint_as_float(u0 << 16) + __uint_as_float(u1 << 16)
                + __uint_as_float(u2 << 16) + __uint_as_float(u3 << 16);
            a1 += __uint_as_float(u0 & 0xFFFF0000u) + __uint_as_float(u1 & 0xFFFF0000u)
                + __uint_as_float(u2 & 0xFFFF0000u) + __uint_as_float(u3 & 0xFFFF0000u);
        }
        for (; j < cnt; ++j) {
            u32 u = ahw[(size_t)__shfl(pk, j, 64) * 128 + 64 + lane];
            a0 += __uint_as_float(u << 16);
            a1 += __uint_as_float(u & 0xFFFF0000u);
        }
    }
    float inv = 1.0f / (float)max(end - beg, 1);
    ahw[node * 128 + lane] = (u32)f2bf(a0 * inv) | ((u32)f2bf(a1 * inv) << 16);
}

// MFMA GEMM layer1: M=128/block, 8 waves, wave tile 16x128, K=128.
__global__ __launch_bounds__(512) void k_gemm1(
    const u16* __restrict__ ax, const float* __restrict__ fc,
    const u16* __restrict__ Bt1, const float* __restrict__ b1,
    const float* __restrict__ relp, u16* __restrict__ ah) {
    __shared__ u16 Bs[128 * 128];   // 32KB; row = 16 chunks; slot p holds chunk p^(col&7)
    int tid = threadIdx.x;
    int lane = tid & 63, w = tid >> 6;
    int mbase = blockIdx.x * 128;
    int r16 = lane & 15;
    int kg = (lane >> 4) * 8;
    int r = min(mbase + w * 16 + r16, NN - 1);
    short8 a[4];
    #pragma unroll
    for (int s = 0; s < 4; ++s)
        a[s] = *(const short8*)(ax + (size_t)r * 128 + s * 32 + kg);
    for (int i = tid; i < 2048; i += 512) {
        int col = i >> 4, p = i & 15;
        ((short8*)Bs)[i] = *(const short8*)(Bt1 + col * 128 + ((p ^ (col & 7)) << 3));
    }
    __syncthreads();
    f32x4 acc[8] = {};
    #pragma unroll
    for (int s = 0; s < 4; ++s) {
        int c = s * 4 + (lane >> 4);
        #pragma unroll
        for (int nf = 0; nf < 8; ++nf) {
            int col = nf * 16 + r16;
            short8 b = ((const short8*)Bs)[col * 16 + (c ^ (col & 7))];
            acc[nf] = __builtin_amdgcn_mfma_f32_16x16x32_bf16(a[s], b, acc[nf], 0, 0, 0);
        }
    }
    #pragma unroll
    for (int reg = 0; reg < 4; ++reg) {
        int row = mbase + w * 16 + (lane >> 4) * 4 + reg;
        if (row >= NN) continue;
        float4 f = *(const float4*)&fc[row * 4];
        #pragma unroll
        for (int nf = 0; nf < 8; ++nf) {
            int cc = nf * 16 + r16;
            float v = acc[nf][reg] + b1[cc]
                    + f.x * relp[cc] + f.y * relp[128 + cc] + f.z * relp[256 + cc];
            ah[(size_t)row * 256 + 128 + cc] = f2bf(fmaxf(v, 0.f));
        }
    }
}

// MFMA GEMM layer2: M=128/block, 8 waves, wave tile 16x128, K=256.
// Epilogue: wave-level segmented max (16 rows -> 1 atomic set when same graph).
__global__ __launch_bounds__(512) void k_gemm2(
    const u16* __restrict__ ah, const u16* __restrict__ Bt2,
    const float* __restrict__ b2, const int* __restrict__ batch,
    unsigned* __restrict__ genc) {
    __shared__ u16 Bs[128 * 256];   // 64KB; row = 32 chunks; slot p holds chunk p^(col&7)
    int tid = threadIdx.x;
    int lane = tid & 63, w = tid >> 6;
    int mbase = blockIdx.x * 128;
    int r16 = lane & 15;
    int kg = (lane >> 4) * 8;
    int r = min(mbase + w * 16 + r16, NN - 1);
    short8 a[8];
    #pragma unroll
    for (int s = 0; s < 8; ++s)
        a[s] = *(const short8*)(ah + (size_t)r * 256 + s * 32 + kg);
    for (int i = tid; i < 4096; i += 512) {
        int col = i >> 5, p = i & 31;
        ((short8*)Bs)[i] = *(const short8*)(Bt2 + col * 256 + ((p ^ (col & 7)) << 3));
    }
    __syncthreads();
    f32x4 acc[8] = {};
    #pragma unroll
    for (int s = 0; s < 8; ++s) {
        int c = s * 4 + (lane >> 4);
        #pragma unroll
        for (int nf = 0; nf < 8; ++nf) {
            int col = nf * 16 + r16;
            short8 b = ((const short8*)Bs)[col * 32 + (c ^ (col & 7))];
            acc[nf] = __builtin_amdgcn_mfma_f32_16x16x32_bf16(a[s], b, acc[nf], 0, 0, 0);
        }
    }
    float bv[8];
    #pragma unroll
    for (int nf = 0; nf < 8; ++nf) bv[nf] = b2[nf * 16 + r16];
    int wbeg = mbase + w * 16;
    if (wbeg >= NN) return;
    int wlast = min(wbeg + 15, NN - 1);
    if (batch[wbeg] == batch[wlast]) {
        // all 16 wave rows (incl. clamped dups) in one graph: reduce across
        // the 4 row-quad lane groups, one atomic set from lanes 0..15.
        int bt = batch[wbeg];
        float vm[8];
        #pragma unroll
        for (int nf = 0; nf < 8; ++nf) {
            f32x4 v4 = acc[nf];
            vm[nf] = fmaxf(fmaxf(v4[0], v4[1]), fmaxf(v4[2], v4[3]));
        }
        #pragma unroll
        for (int nf = 0; nf < 8; ++nf)
            vm[nf] = fmaxf(vm[nf], __shfl_xor(vm[nf], 16, 64));
        #pragma unroll
        for (int nf = 0; nf < 8; ++nf)
            vm[nf] = fmaxf(vm[nf], __shfl_xor(vm[nf], 32, 64));
        if ((lane >> 4) == 0) {
            #pragma unroll
            for (int nf = 0; nf < 8; ++nf)
                atomicMax(&genc[bt * HID + nf * 16 + r16], fenc(vm[nf] + bv[nf]));
        }
    } else {
        int r0 = wbeg + (lane >> 4) * 4;
        if (r0 < NN) {
            if (r0 + 3 < NN && batch[r0] == batch[r0 + 3]) {
                int bt = batch[r0];
                #pragma unroll
                for (int nf = 0; nf < 8; ++nf) {
                    int cc = nf * 16 + r16;
                    f32x4 v4 = acc[nf];
                    float v = fmaxf(fmaxf(v4[0], v4[1]), fmaxf(v4[2], v4[3])) + bv[nf];
                    atomicMax(&genc[bt * HID + cc], fenc(v));
                }
            } else {
                #pragma unroll
                for (int reg = 0; reg < 4; ++reg) {
                    int row = r0 + reg;
                    if (row >= NN) continue;
                    int bt = batch[row];
                    #pragma unroll
                    for (int nf = 0; nf < 8; ++nf) {
                        int cc = nf * 16 + r16;
                        atomicMax(&genc[bt * HID + cc], fenc(acc[nf][reg] + bv[nf]));
                    }
                }
            }
        }
    }
}

__global__ void k_final(const unsigned* __restrict__ genc,
                        const float* __restrict__ lin_w, const float* __restrict__ lin_b,
                        float* __restrict__ out) {
    int gr = blockIdx.x;
    int lane = threadIdx.x;  // 64
    float g0 = fmaxf(fdec(genc[gr * HID + lane]), 0.f);
    float g1 = fmaxf(fdec(genc[gr * HID + 64 + lane]), 0.f);
    #pragma unroll
    for (int c = 0; c < NCLS; ++c) {
        float p = g0 * lin_w[lane * NCLS + c] + g1 * lin_w[(lane + 64) * NCLS + c];
        for (int off = 32; off > 0; off >>= 1)
            p += __shfl_down(p, off, 64);
        if (lane == 0) out[gr * NCLS + c] = p + lin_b[c];
    }
}

extern "C" void kernel_launch(void* const* d_in, const int* in_sizes, int n_in,
                              void* d_out, int out_size, void* d_ws, size_t ws_size,
                              hipStream_t stream) {
    const int* x_tokens   = (const int*)d_in[0];
    const int* edge_index = (const int*)d_in[1];
    const int* edge_type  = (const int*)d_in[2];
    const int* batch      = (const int*)d_in[3];
    const float* emb_table = (const float*)d_in[5];
    const float* rel_table = (const float*)d_in[6];
    const float* w1_l = (const float*)d_in[7];
    const float* b1   = (const float*)d_in[8];
    const float* w1_r = (const float*)d_in[9];
    const float* w2_l = (const float*)d_in[10];
    const float* b2   = (const float*)d_in[11];
    const float* w2_r = (const float*)d_in[12];
    const float* lin_w = (const float*)d_in[13];
    const float* lin_b = (const float*)d_in[14];
    float* out = (float*)d_out;

    const int* src = edge_index;
    const int* dst = edge_index + NE;

    char* ws = (char*)d_ws;
    size_t off = 0;
    auto alloc = [&](size_t bytes) {
        void* p = ws + off;
        off = (off + bytes + 255) & ~(size_t)255;
        return p;
    };
    u16* ax      = (u16*)alloc((size_t)NN * 128 * 2);    // 25.6 MB  [aggx | x]
    u16* ah      = (u16*)alloc((size_t)NN * 256 * 2);    // 51.2 MB  [aggh | h]
    float* fc    = (float*)alloc((size_t)NN * 4 * 4);
    int* offsets = (int*)alloc((size_t)(NN + 1) * 4);
    int* packed  = (int*)alloc((size_t)NE * 4);
    u32* coarse  = (u32*)alloc((size_t)NE * 4);
    int* counts  = (int*)alloc((size_t)NSCAN * 4);
    int* scanned = (int*)alloc((size_t)NSCAN * 4);
    int* gpart   = (int*)alloc((size_t)128 * 4);
    unsigned* genc = (unsigned*)alloc((size_t)NG * HID * 4);
    float* relp  = (float*)alloc((size_t)3 * HID * 4);
    u16* Bt1     = (u16*)alloc((size_t)128 * 128 * 2);
    u16* Bt2     = (u16*)alloc((size_t)128 * 256 * 2);
    (void)ws_size; (void)in_sizes; (void)n_in; (void)out_size;

    const int MT = (NN + 127) / 128;  // 782 GEMM m-tiles

    hipLaunchKernelGGL(k_init,  dim3(1000), dim3(256), 0, stream,
                       genc, relp, Bt1, Bt2, rel_table, w1_l, w1_r, w2_l, w2_r);
    hipLaunchKernelGGL(k_embed, dim3(NN * 32 / 256), dim3(256), 0, stream,
                       x_tokens, emb_table, (u32*)ax);
    hipLaunchKernelGGL(k_cnt,   dim3(NBA), dim3(256), 0, stream, dst, counts);
    hipLaunchKernelGGL(k_gs1,   dim3(GS_NB), dim3(256), 0, stream, counts, gpart);
    hipLaunchKernelGGL(k_gs2,   dim3(1), dim3(128), 0, stream, gpart);
    hipLaunchKernelGGL(k_gs3,   dim3(GS_NB), dim3(256), 0, stream, counts, gpart, scanned);
    hipLaunchKernelGGL(k_part,  dim3(NBA), dim3(256), 0, stream,
                       src, dst, edge_type, scanned, coarse);
    hipLaunchKernelGGL(k_csr,   dim3(NBKT), dim3(256), 0, stream,
                       scanned, coarse, offsets, packed);
    hipLaunchKernelGGL(k_agg1,  dim3(NN / 4), dim3(256), 0, stream,
                       offsets, packed, (u32*)ax, fc);
    hipLaunchKernelGGL(k_gemm1, dim3(MT), dim3(512), 0, stream,
                       ax, fc, Bt1, b1, relp, ah);
    hipLaunchKernelGGL(k_agg2,  dim3(NN / 4), dim3(256), 0, stream,
                       offsets, packed, (u32*)ah);
    hipLaunchKernelGGL(k_gemm2, dim3(MT), dim3(512), 0, stream,
                       ah, Bt2, b2, batch, genc);
    hipLaunchKernelGGL(k_final, dim3(NG), dim3(64), 0, stream, genc, lin_w, lin_b, out);
}

// Round 10
// 165.607 us; speedup vs baseline: 1.1848x; 1.0724x over previous
//
#include <hip/hip_runtime.h>
#include <hip/hip_bf16.h>

#define NN 100000
#define NE 800000
#define NG 2000
#define EMB 64
#define HID 128
#define NCLS 10

#define NBKT 196                       // coarse dst buckets (512 nodes each)
#define EPB 4096                       // edges per counting block
#define NBA ((NE + EPB - 1) / EPB)     // 196 counting blocks

typedef __attribute__((ext_vector_type(8))) short short8;
typedef __attribute__((ext_vector_type(4))) float f32x4;
typedef unsigned short u16;
typedef unsigned int u32;

// monotone float<->uint encoding so unsigned atomicMax == float max
static __device__ __forceinline__ unsigned fenc(float f) {
    unsigned u = __float_as_uint(f);
    return (u & 0x80000000u) ? ~u : (u | 0x80000000u);
}
static __device__ __forceinline__ float fdec(unsigned u) {
    return (u & 0x80000000u) ? __uint_as_float(u & 0x7FFFFFFFu) : __uint_as_float(~u);
}
static __device__ __forceinline__ u16 f2bf(float f) {
    u32 u = __float_as_uint(f);
    return (u16)((u + 0x7FFFu + ((u >> 16) & 1u)) >> 16);
}

// fused prologue: blocks [0,NBA) = coarse histogram; blocks [NBA,..) = embed + init
__global__ __launch_bounds__(256) void k_pre(
    const int* __restrict__ tok, const float* __restrict__ emb,
    const int* __restrict__ dst, int* __restrict__ counts,
    unsigned* __restrict__ genc, float* __restrict__ relp,
    u16* __restrict__ Bt1, u16* __restrict__ Bt2,
    const float* __restrict__ rel_table, const float* __restrict__ w1l,
    const float* __restrict__ w1r, const float* __restrict__ w2l,
    const float* __restrict__ w2r, u32* __restrict__ axw) {
    __shared__ int hist[NBKT];
    int g = blockIdx.x, t = threadIdx.x;
    if (g < NBA) {
        for (int i = t; i < NBKT; i += 256) hist[i] = 0;
        __syncthreads();
        int base = g * EPB;
        for (int j = t; j < EPB; j += 256) {
            int e = base + j;
            if (e < NE) atomicAdd(&hist[dst[e] >> 9], 1);
        }
        __syncthreads();
        for (int i = t; i < NBKT; i += 256)
            counts[i * NBA + g] = hist[i];  // bucket-major
        return;
    }
    int i = (g - NBA) * 256 + t;          // < NN*32 == 3.2M
    {   // embedding -> bf16 into x-half of ax[node][128]
        int n = i >> 5, p = i & 31;
        float2 e = *(const float2*)&emb[tok[n] * EMB + p * 2];
        axw[n * 64 + 32 + p] = (u32)f2bf(e.x) | ((u32)f2bf(e.y) << 16);
    }
    if (i < NG * HID) genc[i] = 0x007FFFFFu;  // fenc(-inf)
    if (i < 3 * HID) {
        int tt = i >> 7, j = i & 127;
        float s = 0.f;
        for (int k = 0; k < 16; ++k)
            s += rel_table[tt * 16 + k] * w1l[(64 + k) * HID + j];
        relp[i] = s;
    }
    if (i < 128 * 128) {
        int c = i >> 7, k = i & 127;
        float w = (k < 64) ? w1l[k * HID + c] : w1r[(k - 64) * HID + c];
        Bt1[c * 128 + k] = f2bf(w);
    }
    if (i < 128 * 256) {
        int c = i >> 8, k = i & 255;
        float w = (k < 128) ? w2l[k * HID + c] : w2r[(k - 128) * HID + c];
        Bt2[c * 256 + k] = f2bf(w);
    }
}

// scan A: per-bucket exclusive prefix over its NBA block-counts + bucket total
__global__ __launch_bounds__(256) void kS1(const int* __restrict__ counts,
                                           int* __restrict__ scanned,
                                           int* __restrict__ bucketT) {
    __shared__ int s[256];
    int b = blockIdx.x, t = threadIdx.x;
    int v = (t < NBA) ? counts[b * NBA + t] : 0;
    s[t] = v;
    __syncthreads();
    for (int off = 1; off < 256; off <<= 1) {
        int u = (t >= off) ? s[t - off] : 0;
        __syncthreads();
        s[t] += u;
        __syncthreads();
    }
    if (t < NBA) scanned[b * NBA + t] = s[t] - v;  // exclusive within bucket
    if (t == 255) bucketT[b] = s[255];
}

// scan B: exclusive scan of bucket totals -> base[b]; base[NBKT] = NE
__global__ __launch_bounds__(256) void kS2(const int* __restrict__ bucketT,
                                           int* __restrict__ base) {
    __shared__ int s[256];
    int t = threadIdx.x;
    int v = (t < NBKT) ? bucketT[t] : 0;
    s[t] = v;
    __syncthreads();
    for (int off = 1; off < 256; off <<= 1) {
        int u = (t >= off) ? s[t - off] : 0;
        __syncthreads();
        s[t] += u;
        __syncthreads();
    }
    if (t < NBKT) base[t] = s[t] - v;
    if (t == 255) base[NBKT] = s[255];  // == NE
}

// pack: src(17) | etype(2)<<17 | dstlow(9)<<19
__global__ __launch_bounds__(256) void k_part(const int* __restrict__ src,
                                              const int* __restrict__ dst,
                                              const int* __restrict__ et,
                                              const int* __restrict__ scanned,
                                              const int* __restrict__ base,
                                              u32* __restrict__ coarse) {
    __shared__ int cur[NBKT];
    int t = threadIdx.x;
    for (int i = t; i < NBKT; i += 256)
        cur[i] = base[i] + scanned[i * NBA + blockIdx.x];
    __syncthreads();
    int b0 = blockIdx.x * EPB;
    for (int j = t; j < EPB; j += 256) {
        int e = b0 + j;
        if (e < NE) {
            int d = dst[e];
            int pos = atomicAdd(&cur[d >> 9], 1);
            coarse[pos] = (u32)src[e] | ((u32)et[e] << 17) | ((u32)(d & 511) << 19);
        }
    }
}

__global__ __launch_bounds__(256) void k_csr(const int* __restrict__ base,
                                             const u32* __restrict__ coarse,
                                             int* __restrict__ offsets,
                                             int* __restrict__ packed) {
    __shared__ int hist[512];
    __shared__ int ex[512];
    __shared__ int ts[256];
    int b = blockIdx.x, t = threadIdx.x;
    int beg = base[b];
    int end = base[b + 1];
    hist[t] = 0; hist[t + 256] = 0;
    __syncthreads();
    for (int i = beg + t; i < end; i += 256)
        atomicAdd(&hist[(coarse[i] >> 19) & 511], 1);
    __syncthreads();
    int a0 = hist[2 * t], a1 = hist[2 * t + 1];
    int sum = a0 + a1;
    ts[t] = sum;
    __syncthreads();
    for (int off = 1; off < 256; off <<= 1) {
        int u = (t >= off) ? ts[t - off] : 0;
        __syncthreads();
        ts[t] += u;
        __syncthreads();
    }
    int ep = ts[t] - sum;
    ex[2 * t] = ep;
    ex[2 * t + 1] = ep + a0;
    __syncthreads();
    int node0 = b * 512;
    if (node0 + 2 * t < NN)     offsets[node0 + 2 * t]     = beg + ex[2 * t];
    if (node0 + 2 * t + 1 < NN) offsets[node0 + 2 * t + 1] = beg + ex[2 * t + 1];
    if (b == NBKT - 1 && t == 0) offsets[NN] = NE;
    hist[2 * t] = beg + ex[2 * t];
    hist[2 * t + 1] = beg + ex[2 * t + 1];
    __syncthreads();
    for (int i = beg + t; i < end; i += 256) {
        u32 pk = coarse[i];
        int pos = atomicAdd(&hist[(pk >> 19) & 511], 1);
        packed[pos] = (int)(pk & 0x1FFFFu) | (int)(((pk >> 17) & 3u) << 20);
    }
}

// gather1: mean of x[src] + type fractions. One wave per node; quarter-wave per edge
// (4 edges per VMEM instruction, uint2 per lane).
__global__ __launch_bounds__(256) void k_agg1(
    const int* __restrict__ offsets, const int* __restrict__ packed,
    u32* __restrict__ axw, float* __restrict__ fc) {
    int node = (blockIdx.x * 256 + threadIdx.x) >> 6;
    int lane = threadIdx.x & 63;
    int qr = lane >> 4;        // 0..3
    int ql = lane & 15;
    int beg = offsets[node], end = offsets[node + 1];
    float a0 = 0.f, a1 = 0.f, a2 = 0.f, a3 = 0.f;
    int c0 = 0, c1 = 0, c2 = 0;
    for (int cb = beg; cb < end; cb += 64) {
        int pk = packed[min(cb + lane, NE - 1)];
        int cnt = min(end - cb, 64);
        int j = 0;
        for (; j + 8 <= cnt; j += 8) {
            #pragma unroll
            for (int q = 0; q < 2; ++q) {
                int p = __shfl(pk, j + q * 4 + qr, 64);
                uint2 v = *(const uint2*)&axw[(p & 0xFFFFF) * 64 + 32 + 2 * ql];
                a0 += __uint_as_float(v.x << 16);
                a1 += __uint_as_float(v.x & 0xFFFF0000u);
                a2 += __uint_as_float(v.y << 16);
                a3 += __uint_as_float(v.y & 0xFFFF0000u);
                int tt = p >> 20;
                c0 += (tt == 0); c1 += (tt == 1); c2 += (tt == 2);
            }
        }
        for (; j < cnt; j += 4) {
            int idx = j + qr;
            if (idx < cnt) {
                int p = __shfl(pk, idx, 64);
                uint2 v = *(const uint2*)&axw[(p & 0xFFFFF) * 64 + 32 + 2 * ql];
                a0 += __uint_as_float(v.x << 16);
                a1 += __uint_as_float(v.x & 0xFFFF0000u);
                a2 += __uint_as_float(v.y << 16);
                a3 += __uint_as_float(v.y & 0xFFFF0000u);
                int tt = p >> 20;
                c0 += (tt == 0); c1 += (tt == 1); c2 += (tt == 2);
            }
        }
    }
    a0 += __shfl_xor(a0, 16, 64); a0 += __shfl_xor(a0, 32, 64);
    a1 += __shfl_xor(a1, 16, 64); a1 += __shfl_xor(a1, 32, 64);
    a2 += __shfl_xor(a2, 16, 64); a2 += __shfl_xor(a2, 32, 64);
    a3 += __shfl_xor(a3, 16, 64); a3 += __shfl_xor(a3, 32, 64);
    c0 += __shfl_xor(c0, 16, 64); c0 += __shfl_xor(c0, 32, 64);
    c1 += __shfl_xor(c1, 16, 64); c1 += __shfl_xor(c1, 32, 64);
    c2 += __shfl_xor(c2, 16, 64); c2 += __shfl_xor(c2, 32, 64);
    float inv = 1.0f / (float)max(end - beg, 1);
    if (qr == 0) {
        uint2 o;
        o.x = (u32)f2bf(a0 * inv) | ((u32)f2bf(a1 * inv) << 16);
        o.y = (u32)f2bf(a2 * inv) | ((u32)f2bf(a3 * inv) << 16);
        *(uint2*)&axw[node * 64 + 2 * ql] = o;
    }
    if (lane == 0)
        *(float4*)&fc[node * 4] = make_float4(c0 * inv, c1 * inv, c2 * inv, 0.f);
}

// gather2: mean of h[src]. One wave per node; half-wave per edge
// (2 edges per VMEM instruction, uint2 per lane).
__global__ __launch_bounds__(256) void k_agg2(
    const int* __restrict__ offsets, const int* __restrict__ packed,
    u32* __restrict__ ahw) {
    int node = (blockIdx.x * 256 + threadIdx.x) >> 6;
    int lane = threadIdx.x & 63;
    int half = lane >> 5, fl = lane & 31;
    int beg = offsets[node], end = offsets[node + 1];
    float a0 = 0.f, a1 = 0.f, a2 = 0.f, a3 = 0.f;
    for (int cb = beg; cb < end; cb += 64) {
        int pk = packed[min(cb + lane, NE - 1)] & 0xFFFFF;
        int cnt = min(end - cb, 64);
        int j = 0;
        for (; j + 8 <= cnt; j += 8) {
            #pragma unroll
            for (int q = 0; q < 4; ++q) {
                int p = __shfl(pk, j + q * 2 + half, 64);
                uint2 v = *(const uint2*)&ahw[(size_t)p * 128 + 64 + 2 * fl];
                a0 += __uint_as_float(v.x << 16);
                a1 += __uint_as_float(v.x & 0xFFFF0000u);
                a2 += __uint_as_float(v.y << 16);
                a3 += __uint_as_float(v.y & 0xFFFF0000u);
            }
        }
        for (; j < cnt; j += 2) {
            int idx = j + half;
            if (idx < cnt) {
                int p = __shfl(pk, idx, 64);
                uint2 v = *(const uint2*)&ahw[(size_t)p * 128 + 64 + 2 * fl];
                a0 += __uint_as_float(v.x << 16);
                a1 += __uint_as_float(v.x & 0xFFFF0000u);
                a2 += __uint_as_float(v.y << 16);
                a3 += __uint_as_float(v.y & 0xFFFF0000u);
            }
        }
    }
    a0 += __shfl_xor(a0, 32, 64);
    a1 += __shfl_xor(a1, 32, 64);
    a2 += __shfl_xor(a2, 32, 64);
    a3 += __shfl_xor(a3, 32, 64);
    float inv = 1.0f / (float)max(end - beg, 1);
    if (half == 0) {
        uint2 o;
        o.x = (u32)f2bf(a0 * inv) | ((u32)f2bf(a1 * inv) << 16);
        o.y = (u32)f2bf(a2 * inv) | ((u32)f2bf(a3 * inv) << 16);
        *(uint2*)&ahw[node * 128 + 2 * fl] = o;
    }
}

// MFMA GEMM layer1: M=128/block, 8 waves, wave tile 16x128, K=128.
__global__ __launch_bounds__(512) void k_gemm1(
    const u16* __restrict__ ax, const float* __restrict__ fc,
    const u16* __restrict__ Bt1, const float* __restrict__ b1,
    const float* __restrict__ relp, u16* __restrict__ ah) {
    __shared__ u16 Bs[128 * 128];   // 32KB; slot p holds chunk p^(col&7)
    int tid = threadIdx.x;
    int lane = tid & 63, w = tid >> 6;
    int mbase = blockIdx.x * 128;
    int r16 = lane & 15;
    int kg = (lane >> 4) * 8;
    int r = min(mbase + w * 16 + r16, NN - 1);
    short8 a[4];
    #pragma unroll
    for (int s = 0; s < 4; ++s)
        a[s] = *(const short8*)(ax + (size_t)r * 128 + s * 32 + kg);
    for (int i = tid; i < 2048; i += 512) {
        int col = i >> 4, p = i & 15;
        ((short8*)Bs)[i] = *(const short8*)(Bt1 + col * 128 + ((p ^ (col & 7)) << 3));
    }
    __syncthreads();
    f32x4 acc[8] = {};
    #pragma unroll
    for (int s = 0; s < 4; ++s) {
        int c = s * 4 + (lane >> 4);
        #pragma unroll
        for (int nf = 0; nf < 8; ++nf) {
            int col = nf * 16 + r16;
            short8 b = ((const short8*)Bs)[col * 16 + (c ^ (col & 7))];
            acc[nf] = __builtin_amdgcn_mfma_f32_16x16x32_bf16(a[s], b, acc[nf], 0, 0, 0);
        }
    }
    #pragma unroll
    for (int reg = 0; reg < 4; ++reg) {
        int row = mbase + w * 16 + (lane >> 4) * 4 + reg;
        if (row >= NN) continue;
        float4 f = *(const float4*)&fc[row * 4];
        #pragma unroll
        for (int nf = 0; nf < 8; ++nf) {
            int cc = nf * 16 + r16;
            float v = acc[nf][reg] + b1[cc]
                    + f.x * relp[cc] + f.y * relp[128 + cc] + f.z * relp[256 + cc];
            ah[(size_t)row * 256 + 128 + cc] = f2bf(fmaxf(v, 0.f));
        }
    }
}

// MFMA GEMM layer2: M=128/block, 8 waves, wave tile 16x128, K=256.
// Epilogue: wave-level segmented max (16 rows -> 1 atomic set when same graph).
__global__ __launch_bounds__(512) void k_gemm2(
    const u16* __restrict__ ah, const u16* __restrict__ Bt2,
    const float* __restrict__ b2, const int* __restrict__ batch,
    unsigned* __restrict__ genc) {
    __shared__ u16 Bs[128 * 256];   // 64KB; slot p holds chunk p^(col&7)
    int tid = threadIdx.x;
    int lane = tid & 63, w = tid >> 6;
    int mbase = blockIdx.x * 128;
    int r16 = lane & 15;
    int kg = (lane >> 4) * 8;
    int r = min(mbase + w * 16 + r16, NN - 1);
    short8 a[8];
    #pragma unroll
    for (int s = 0; s < 8; ++s)
        a[s] = *(const short8*)(ah + (size_t)r * 256 + s * 32 + kg);
    for (int i = tid; i < 4096; i += 512) {
        int col = i >> 5, p = i & 31;
        ((short8*)Bs)[i] = *(const short8*)(Bt2 + col * 256 + ((p ^ (col & 7)) << 3));
    }
    __syncthreads();
    f32x4 acc[8] = {};
    #pragma unroll
    for (int s = 0; s < 8; ++s) {
        int c = s * 4 + (lane >> 4);
        #pragma unroll
        for (int nf = 0; nf < 8; ++nf) {
            int col = nf * 16 + r16;
            short8 b = ((const short8*)Bs)[col * 32 + (c ^ (col & 7))];
            acc[nf] = __builtin_amdgcn_mfma_f32_16x16x32_bf16(a[s], b, acc[nf], 0, 0, 0);
        }
    }
    float bv[8];
    #pragma unroll
    for (int nf = 0; nf < 8; ++nf) bv[nf] = b2[nf * 16 + r16];
    int wbeg = mbase + w * 16;
    if (wbeg >= NN) return;
    int wlast = min(wbeg + 15, NN - 1);
    if (batch[wbeg] == batch[wlast]) {
        int bt = batch[wbeg];
        float vm[8];
        #pragma unroll
        for (int nf = 0; nf < 8; ++nf) {
            f32x4 v4 = acc[nf];
            vm[nf] = fmaxf(fmaxf(v4[0], v4[1]), fmaxf(v4[2], v4[3]));
        }
        #pragma unroll
        for (int nf = 0; nf < 8; ++nf)
            vm[nf] = fmaxf(vm[nf], __shfl_xor(vm[nf], 16, 64));
        #pragma unroll
        for (int nf = 0; nf < 8; ++nf)
            vm[nf] = fmaxf(vm[nf], __shfl_xor(vm[nf], 32, 64));
        if ((lane >> 4) == 0) {
            #pragma unroll
            for (int nf = 0; nf < 8; ++nf)
                atomicMax(&genc[bt * HID + nf * 16 + r16], fenc(vm[nf] + bv[nf]));
        }
    } else {
        int r0 = wbeg + (lane >> 4) * 4;
        if (r0 < NN) {
            if (r0 + 3 < NN && batch[r0] == batch[r0 + 3]) {
                int bt = batch[r0];
                #pragma unroll
                for (int nf = 0; nf < 8; ++nf) {
                    int cc = nf * 16 + r16;
                    f32x4 v4 = acc[nf];
                    float v = fmaxf(fmaxf(v4[0], v4[1]), fmaxf(v4[2], v4[3])) + bv[nf];
                    atomicMax(&genc[bt * HID + cc], fenc(v));
                }
            } else {
                #pragma unroll
                for (int reg = 0; reg < 4; ++reg) {
                    int row = r0 + reg;
                    if (row >= NN) continue;
                    int bt = batch[row];
                    #pragma unroll
                    for (int nf = 0; nf < 8; ++nf) {
                        int cc = nf * 16 + r16;
                        atomicMax(&genc[bt * HID + cc], fenc(acc[nf][reg] + bv[nf]));
                    }
                }
            }
        }
    }
}

__global__ void k_final(const unsigned* __restrict__ genc,
                        const float* __restrict__ lin_w, const float* __restrict__ lin_b,
                        float* __restrict__ out) {
    int gr = blockIdx.x;
    int lane = threadIdx.x;  // 64
    float g0 = fmaxf(fdec(genc[gr * HID + lane]), 0.f);
    float g1 = fmaxf(fdec(genc[gr * HID + 64 + lane]), 0.f);
    #pragma unroll
    for (int c = 0; c < NCLS; ++c) {
        float p = g0 * lin_w[lane * NCLS + c] + g1 * lin_w[(lane + 64) * NCLS + c];
        for (int off = 32; off > 0; off >>= 1)
            p += __shfl_down(p, off, 64);
        if (lane == 0) out[gr * NCLS + c] = p + lin_b[c];
    }
}

extern "C" void kernel_launch(void* const* d_in, const int* in_sizes, int n_in,
                              void* d_out, int out_size, void* d_ws, size_t ws_size,
                              hipStream_t stream) {
    const int* x_tokens   = (const int*)d_in[0];
    const int* edge_index = (const int*)d_in[1];
    const int* edge_type  = (const int*)d_in[2];
    const int* batch      = (const int*)d_in[3];
    const float* emb_table = (const float*)d_in[5];
    const float* rel_table = (const float*)d_in[6];
    const float* w1_l = (const float*)d_in[7];
    const float* b1   = (const float*)d_in[8];
    const float* w1_r = (const float*)d_in[9];
    const float* w2_l = (const float*)d_in[10];
    const float* b2   = (const float*)d_in[11];
    const float* w2_r = (const float*)d_in[12];
    const float* lin_w = (const float*)d_in[13];
    const float* lin_b = (const float*)d_in[14];
    float* out = (float*)d_out;

    const int* src = edge_index;
    const int* dst = edge_index + NE;

    char* ws = (char*)d_ws;
    size_t off = 0;
    auto alloc = [&](size_t bytes) {
        void* p = ws + off;
        off = (off + bytes + 255) & ~(size_t)255;
        return p;
    };
    u16* ax      = (u16*)alloc((size_t)NN * 128 * 2);    // 25.6 MB  [aggx | x]
    u16* ah      = (u16*)alloc((size_t)NN * 256 * 2);    // 51.2 MB  [aggh | h]
    float* fc    = (float*)alloc((size_t)NN * 4 * 4);
    int* offsets = (int*)alloc((size_t)(NN + 1) * 4);
    int* packed  = (int*)alloc((size_t)NE * 4);
    u32* coarse  = (u32*)alloc((size_t)NE * 4);
    int* counts  = (int*)alloc((size_t)NBKT * NBA * 4);
    int* scanned = (int*)alloc((size_t)NBKT * NBA * 4);
    int* bucketT = (int*)alloc((size_t)NBKT * 4);
    int* base    = (int*)alloc((size_t)(NBKT + 1) * 4);
    unsigned* genc = (unsigned*)alloc((size_t)NG * HID * 4);
    float* relp  = (float*)alloc((size_t)3 * HID * 4);
    u16* Bt1     = (u16*)alloc((size_t)128 * 128 * 2);
    u16* Bt2     = (u16*)alloc((size_t)128 * 256 * 2);
    (void)ws_size; (void)in_sizes; (void)n_in; (void)out_size;

    const int MT = (NN + 127) / 128;          // 782 GEMM m-tiles
    const int PRE = NBA + NN * 32 / 256;      // 196 + 12500

    hipLaunchKernelGGL(k_pre,   dim3(PRE), dim3(256), 0, stream,
                       x_tokens, emb_table, dst, counts, genc, relp, Bt1, Bt2,
                       rel_table, w1_l, w1_r, w2_l, w2_r, (u32*)ax);
    hipLaunchKernelGGL(kS1,     dim3(NBKT), dim3(256), 0, stream, counts, scanned, bucketT);
    hipLaunchKernelGGL(kS2,     dim3(1), dim3(256), 0, stream, bucketT, base);
    hipLaunchKernelGGL(k_part,  dim3(NBA), dim3(256), 0, stream,
                       src, dst, edge_type, scanned, base, coarse);
    hipLaunchKernelGGL(k_csr,   dim3(NBKT), dim3(256), 0, stream,
                       base, coarse, offsets, packed);
    hipLaunchKernelGGL(k_agg1,  dim3(NN / 4), dim3(256), 0, stream,
                       offsets, packed, (u32*)ax, fc);
    hipLaunchKernelGGL(k_gemm1, dim3(MT), dim3(512), 0, stream,
                       ax, fc, Bt1, b1, relp, ah);
    hipLaunchKernelGGL(k_agg2,  dim3(NN / 4), dim3(256), 0, stream,
                       offsets, packed, (u32*)ah);
    hipLaunchKernelGGL(k_gemm2, dim3(MT), dim3(512), 0, stream,
                       ah, Bt2, b2, batch, genc);
    hipLaunchKernelGGL(k_final, dim3(NG), dim3(64), 0, stream, genc, lin_w, lin_b, out);
}